// Round 3
// baseline (248.400 us; speedup 1.0000x reference)
//
#include <hip/hip_runtime.h>
#include <cstdint>
#include <cmath>

// ---------------------------------------------------------------------------
// Shapes (fixed by reference setup): B=8, N=100000, D=64, H=64, E=3.2e6
// in_dim = 3*D+4 = 196. Output = 2 floats.
//
// NOTE: harness passes ALL integer inputs as int32 (per contract:
// "integer -> const int*") — edge_index is (2,E) int32 here, NOT int64.
//
// All scratch lives in module-static __device__ globals. Everything is
// zeroed by zero_kernel at the start of every call — no cross-call state.
// ---------------------------------------------------------------------------

#define MAXN (1 << 17)   // 131072 >= N=100000

__device__ float              g_sum[512];     // per-(b,d) sum
__device__ float              g_sq[512];      // per-(b,d) sumsq
__device__ unsigned           g_max[512];     // per-(b,d) max, order-preserving enc
__device__ unsigned long long g_degSums[2];   // degree sum, sumsq (exact ints)
__device__ unsigned           g_deg[MAXN];    // degree histogram

__device__ __forceinline__ unsigned enc_f32(float f) {
    unsigned u = __float_as_uint(f);
    return (u & 0x80000000u) ? ~u : (u | 0x80000000u);
}
__device__ __forceinline__ float dec_f32(unsigned u) {
    return (u & 0x80000000u) ? __uint_as_float(u ^ 0x80000000u) : __uint_as_float(~u);
}

// ---- Kernel 0: zero all scratch -------------------------------------------
__global__ __launch_bounds__(256) void zero_kernel(int N)
{
    int i = blockIdx.x * blockDim.x + threadIdx.x;
    int stride = gridDim.x * blockDim.x;
    if (i < 512) { g_sum[i] = 0.f; g_sq[i] = 0.f; g_max[i] = 0u; }
    if (i < 2)   { g_degSums[i] = 0ull; }
    for (int j = i; j < N; j += stride) g_deg[j] = 0u;
}

// ---- Kernel 1: per-(b,d) sum / sumsq / max over the node axis -------------
__global__ __launch_bounds__(256) void xstats_kernel(
    const float* __restrict__ x, int N, int blocksPerBatch, int rowsPerBlock)
{
    const int b   = blockIdx.x / blocksPerBatch;
    const int blk = blockIdx.x % blocksPerBatch;
    const int tid = threadIdx.x;
    const int d4  = tid & 15;   // which group of 4 columns
    const int rg  = tid >> 4;   // row sub-group 0..15

    const int rowStart = blk * rowsPerBlock;
    const int rowEnd   = min(N, rowStart + rowsPerBlock);

    float s0 = 0.f, s1 = 0.f, s2 = 0.f, s3 = 0.f;
    float q0 = 0.f, q1 = 0.f, q2 = 0.f, q3 = 0.f;
    float m0 = -INFINITY, m1 = -INFINITY, m2 = -INFINITY, m3 = -INFINITY;

    const float* xb = x + (size_t)b * (size_t)N * 64 + d4 * 4;
    for (int r = rowStart + rg; r < rowEnd; r += 16) {
        float4 v = *reinterpret_cast<const float4*>(xb + (size_t)r * 64);
        s0 += v.x; s1 += v.y; s2 += v.z; s3 += v.w;
        q0 = fmaf(v.x, v.x, q0); q1 = fmaf(v.y, v.y, q1);
        q2 = fmaf(v.z, v.z, q2); q3 = fmaf(v.w, v.w, q3);
        m0 = fmaxf(m0, v.x); m1 = fmaxf(m1, v.y);
        m2 = fmaxf(m2, v.z); m3 = fmaxf(m3, v.w);
    }

    __shared__ float ls[256 * 4];
    __shared__ float lq[256 * 4];
    __shared__ float lm[256 * 4];
    ls[tid*4+0]=s0; ls[tid*4+1]=s1; ls[tid*4+2]=s2; ls[tid*4+3]=s3;
    lq[tid*4+0]=q0; lq[tid*4+1]=q1; lq[tid*4+2]=q2; lq[tid*4+3]=q3;
    lm[tid*4+0]=m0; lm[tid*4+1]=m1; lm[tid*4+2]=m2; lm[tid*4+3]=m3;
    __syncthreads();

    for (int off = 8; off; off >>= 1) {
        if (rg < off) {
            int o  = (tid + off * 16) * 4;
            int me = tid * 4;
            #pragma unroll
            for (int j = 0; j < 4; ++j) {
                ls[me+j] += ls[o+j];
                lq[me+j] += lq[o+j];
                lm[me+j]  = fmaxf(lm[me+j], lm[o+j]);
            }
        }
        __syncthreads();
    }

    if (rg == 0) {
        #pragma unroll
        for (int j = 0; j < 4; ++j) {
            int cell = b * 64 + d4 * 4 + j;
            atomicAdd(&g_sum[cell], ls[tid*4+j]);
            atomicAdd(&g_sq[cell],  lq[tid*4+j]);
            atomicMax(&g_max[cell], enc_f32(lm[tid*4+j]));
        }
    }
}

// ---- Kernel 2: degree histogram over row 1 of edge_index (int32!) ---------
__global__ __launch_bounds__(256) void degree_kernel(
    const int* __restrict__ ei, int E, int N)
{
    int i = blockIdx.x * blockDim.x + threadIdx.x;
    const int stride = gridDim.x * blockDim.x;
    const int* row1 = ei + E;
    for (; i < E; i += stride) {
        int idx = row1[i];
        if (idx >= 0 && idx < N) atomicAdd(&g_deg[idx], 1u);
    }
}

// ---- Kernel 3: exact integer sum / sumsq of degrees -----------------------
__global__ __launch_bounds__(256) void degstat_kernel(int N)
{
    int i = blockIdx.x * blockDim.x + threadIdx.x;
    const int stride = gridDim.x * blockDim.x;
    unsigned long long s = 0, q = 0;
    for (; i < N; i += stride) {
        unsigned long long d = g_deg[i];
        s += d;
        q += d * d;
    }
    #pragma unroll
    for (int off = 32; off; off >>= 1) {
        s += __shfl_down(s, off, 64);
        q += __shfl_down(q, off, 64);
    }
    if ((threadIdx.x & 63) == 0) {
        atomicAdd(&g_degSums[0], s);
        atomicAdd(&g_degSums[1], q);
    }
}

// ---- Kernel 4: finalize stats + MLP + output ------------------------------
__global__ __launch_bounds__(256) void final_kernel(
    int N, long long E,
    const float* __restrict__ W1, const float* __restrict__ b1,
    const float* __restrict__ W2, const float* __restrict__ b2,
    const float* __restrict__ W3, const float* __restrict__ b3,
    float* __restrict__ out)
{
    __shared__ float gf[8][200];   // 196 used
    __shared__ float h1[8][64];
    __shared__ float h2[8][32];
    __shared__ float raw[8], rnd[8];

    const int tid = threadIdx.x;

    // per-(b,d) mean / max / std
    for (int i = tid; i < 512; i += 256) {
        int b = i >> 6, d = i & 63;
        float sum = g_sum[i], sq = g_sq[i];
        float mean = sum / (float)N;
        float var  = fmaxf(0.f, sq - sum * sum / (float)N) / (float)(N - 1);
        gf[b][d]       = mean;
        gf[b][64 + d]  = dec_f32(g_max[i]);
        gf[b][128 + d] = sqrtf(var);
    }
    if (tid < 32) {
        int b = tid >> 2, k = tid & 3;
        double dsum = (double)g_degSums[0];
        double dsq  = (double)g_degSums[1];
        double avg  = dsum / (double)N;
        double var  = (dsq - dsum * dsum / (double)N) / (double)(N - 1);
        long long num_edges = E / 2;
        double max_edges = (double)N * (double)(N - 1) / 2.0;
        float v;
        if      (k == 0) v = (float)avg;
        else if (k == 1) v = (float)sqrt(var);
        else if (k == 2) v = (float)((double)num_edges / max_edges);
        else             v = (float)(log((double)N + 1.0) / 10.0);
        gf[b][192 + k] = v;
    }
    __syncthreads();

    // layer 1: [8,196] x [196,64]
    if (tid < 64) {
        int d = tid;
        for (int b = 0; b < 8; ++b) {
            float acc = b1[d];
            for (int k = 0; k < 196; ++k)
                acc = fmaf(gf[b][k], W1[k * 64 + d], acc);
            h1[b][d] = fmaxf(acc, 0.f);
        }
    }
    __syncthreads();

    // layer 2: [8,64] x [64,32]
    if (tid < 32) {
        int d = tid;
        for (int b = 0; b < 8; ++b) {
            float acc = b2[d];
            for (int k = 0; k < 64; ++k)
                acc = fmaf(h1[b][k], W2[k * 32 + d], acc);
            h2[b][d] = fmaxf(acc, 0.f);
        }
    }
    __syncthreads();

    // layer 3 + sigmoid + straight-through round
    if (tid < 8) {
        float acc = b3[0];
        for (int k = 0; k < 32; ++k)
            acc = fmaf(h2[tid][k], W3[k], acc);
        float r = 1.f / (1.f + expf(-acc));
        raw[tid] = r;
        float cont = 3.0f + r * 47.0f;
        rnd[tid] = rintf(cont);   // round-half-to-even, matches jnp.round
    }
    __syncthreads();

    if (tid == 0) {
        float sr = 0.f, sw = 0.f;
        for (int b = 0; b < 8; ++b) { sr += rnd[b]; sw += raw[b]; }
        out[0] = sr * 0.125f;
        out[1] = sw * 0.125f;
    }
}

// ---------------------------------------------------------------------------
extern "C" void kernel_launch(void* const* d_in, const int* in_sizes, int n_in,
                              void* d_out, int out_size, void* d_ws, size_t ws_size,
                              hipStream_t stream)
{
    const float* x  = (const float*)d_in[0];
    const int*   ei = (const int*)d_in[1];      // int32 per harness contract
    const float* W1 = (const float*)d_in[2];
    const float* b1 = (const float*)d_in[3];
    const float* W2 = (const float*)d_in[4];
    const float* b2 = (const float*)d_in[5];
    const float* W3 = (const float*)d_in[6];
    const float* b3 = (const float*)d_in[7];
    float* out = (float*)d_out;

    int N = in_sizes[0] / (8 * 64);            // B=8, D=64
    if (N > MAXN) N = MAXN;                    // fixed shape guard (N=100000)
    const int E = in_sizes[1] / 2;             // edge count (row-major (2,E))

    zero_kernel<<<512, 256, 0, stream>>>(N);

    const int bpb = 256;                       // blocks per batch for xstats
    const int rpb = (N + bpb - 1) / bpb;       // rows per block
    xstats_kernel<<<8 * bpb, 256, 0, stream>>>(x, N, bpb, rpb);

    degree_kernel<<<1024, 256, 0, stream>>>(ei, E, N);

    degstat_kernel<<<128, 256, 0, stream>>>(N);

    final_kernel<<<1, 256, 0, stream>>>(N, (long long)E,
                                        W1, b1, W2, b2, W3, b3, out);
}

// Round 4
// 197.797 us; speedup vs baseline: 1.2558x; 1.2558x over previous
//
#include <hip/hip_runtime.h>
#include <cstdint>
#include <cmath>

// ---------------------------------------------------------------------------
// Shapes (fixed by reference setup): B=8, N=100000, D=64, H=64, E=3.2e6
// in_dim = 3*D+4 = 196. Output = 2 floats. edge_index arrives as int32.
//
// Degree stats via one-pass bucket sort (no full-histogram global atomics):
//   A: per-segment per-bucket counts (LDS, then plain stores)
//   B: prefix-sum -> per-(segment,bucket) scatter offsets (1 block)
//   C: scatter edges into bucket-sorted order
//   D: per-bucket 1024-bin LDS histogram -> exact u64 sum / sumsq of degrees
// ---------------------------------------------------------------------------

#define NB      128          // buckets = idx >> BSHIFT
#define BSHIFT  10           // 1024 bins per bucket
#define NBINS   (1 << BSHIFT)
#define SEG     128          // edge-list segments
#define MAXE    (1 << 22)    // 4M >= E=3.2M

__device__ unsigned           g_cnt[SEG][NB];
__device__ unsigned           g_offs[SEG][NB];
__device__ unsigned           g_base[NB + 1];
__device__ int                g_sorted[MAXE];
__device__ float              g_sum[512];     // per-(b,d) sum
__device__ float              g_sq[512];      // per-(b,d) sumsq
__device__ unsigned           g_max[512];     // per-(b,d) max, order-preserving enc
__device__ unsigned long long g_degSums[2];   // degree sum, sumsq (exact ints)

__device__ __forceinline__ unsigned enc_f32(float f) {
    unsigned u = __float_as_uint(f);
    return (u & 0x80000000u) ? ~u : (u | 0x80000000u);
}
__device__ __forceinline__ float dec_f32(unsigned u) {
    return (u & 0x80000000u) ? __uint_as_float(u ^ 0x80000000u) : __uint_as_float(~u);
}

// ---- A: per-segment bucket counts (also clears the small stat scratch) ----
__global__ __launch_bounds__(256) void bucket_count_kernel(
    const int* __restrict__ ei, int E, int N)
{
    const int s = blockIdx.x, tid = threadIdx.x;
    if (s == 0) {   // clear stats scratch (consumed by later kernels only)
        for (int i = tid; i < 512; i += 256) { g_sum[i] = 0.f; g_sq[i] = 0.f; g_max[i] = 0u; }
        if (tid < 2) g_degSums[tid] = 0ull;
    }
    __shared__ unsigned h[NB];
    if (tid < NB) h[tid] = 0u;
    __syncthreads();

    const int* row1 = ei + E;
    const int per = (E + SEG - 1) / SEG;
    const int lo = s * per, hi = min(E, lo + per);
    for (int i = lo + tid; i < hi; i += 256) {
        unsigned idx = (unsigned)row1[i];
        if (idx < (unsigned)N) atomicAdd(&h[idx >> BSHIFT], 1u);
    }
    __syncthreads();
    if (tid < NB) g_cnt[s][tid] = h[tid];
}

// ---- B: offsets (single block, thread b owns bucket b) --------------------
__global__ __launch_bounds__(NB) void bucket_offset_kernel()
{
    const int b = threadIdx.x;   // 0..NB-1
    unsigned tot = 0;
    for (int s = 0; s < SEG; ++s) tot += g_cnt[s][b];
    __shared__ unsigned t[NB];
    __shared__ unsigned base[NB + 1];
    t[b] = tot;
    __syncthreads();
    if (b == 0) {
        unsigned acc = 0;
        for (int i = 0; i < NB; ++i) { base[i] = acc; acc += t[i]; }
        base[NB] = acc;
    }
    __syncthreads();
    unsigned run = base[b];
    for (int s = 0; s < SEG; ++s) { g_offs[s][b] = run; run += g_cnt[s][b]; }
    g_base[b] = base[b];
    if (b == 0) g_base[NB] = base[NB];
}

// ---- C: scatter edges into bucket-sorted order ----------------------------
__global__ __launch_bounds__(256) void bucket_scatter_kernel(
    const int* __restrict__ ei, int E, int N)
{
    const int s = blockIdx.x, tid = threadIdx.x;
    __shared__ unsigned cur[NB];
    if (tid < NB) cur[tid] = g_offs[s][tid];
    __syncthreads();

    const int* row1 = ei + E;
    const int per = (E + SEG - 1) / SEG;
    const int lo = s * per, hi = min(E, lo + per);
    for (int i = lo + tid; i < hi; i += 256) {
        unsigned idx = (unsigned)row1[i];
        if (idx < (unsigned)N) {
            unsigned p = atomicAdd(&cur[idx >> BSHIFT], 1u);
            g_sorted[p] = (int)idx;
        }
    }
}

// ---- D: per-bucket histogram -> exact degree sum / sumsq ------------------
__global__ __launch_bounds__(256) void bucket_hist_kernel()
{
    const int b = blockIdx.x, tid = threadIdx.x;
    const unsigned lo = g_base[b], hi = g_base[b + 1];

    __shared__ unsigned h[NBINS];
    for (int i = tid; i < NBINS; i += 256) h[i] = 0u;
    __syncthreads();

    for (unsigned i = lo + tid; i < hi; i += 256)
        atomicAdd(&h[(unsigned)g_sorted[i] & (NBINS - 1)], 1u);
    __syncthreads();

    unsigned long long s = 0, q = 0;
    for (int i = tid; i < NBINS; i += 256) {
        unsigned long long c = h[i];
        s += c;
        q += c * c;
    }
    #pragma unroll
    for (int off = 32; off; off >>= 1) {
        s += __shfl_down(s, off, 64);
        q += __shfl_down(q, off, 64);
    }
    if ((tid & 63) == 0 && (s | q)) {
        atomicAdd(&g_degSums[0], s);
        atomicAdd(&g_degSums[1], q);
    }
}

// ---- xstats: per-(b,d) sum / sumsq / max over the node axis ---------------
__global__ __launch_bounds__(256) void xstats_kernel(
    const float* __restrict__ x, int N, int blocksPerBatch, int rowsPerBlock)
{
    const int b   = blockIdx.x / blocksPerBatch;
    const int blk = blockIdx.x % blocksPerBatch;
    const int tid = threadIdx.x;
    const int d4  = tid & 15;
    const int rg  = tid >> 4;

    const int rowStart = blk * rowsPerBlock;
    const int rowEnd   = min(N, rowStart + rowsPerBlock);

    float s0 = 0.f, s1 = 0.f, s2 = 0.f, s3 = 0.f;
    float q0 = 0.f, q1 = 0.f, q2 = 0.f, q3 = 0.f;
    float m0 = -INFINITY, m1 = -INFINITY, m2 = -INFINITY, m3 = -INFINITY;

    const float* xb = x + (size_t)b * (size_t)N * 64 + d4 * 4;
    for (int r = rowStart + rg; r < rowEnd; r += 16) {
        float4 v = *reinterpret_cast<const float4*>(xb + (size_t)r * 64);
        s0 += v.x; s1 += v.y; s2 += v.z; s3 += v.w;
        q0 = fmaf(v.x, v.x, q0); q1 = fmaf(v.y, v.y, q1);
        q2 = fmaf(v.z, v.z, q2); q3 = fmaf(v.w, v.w, q3);
        m0 = fmaxf(m0, v.x); m1 = fmaxf(m1, v.y);
        m2 = fmaxf(m2, v.z); m3 = fmaxf(m3, v.w);
    }

    __shared__ float ls[256 * 4];
    __shared__ float lq[256 * 4];
    __shared__ float lm[256 * 4];
    ls[tid*4+0]=s0; ls[tid*4+1]=s1; ls[tid*4+2]=s2; ls[tid*4+3]=s3;
    lq[tid*4+0]=q0; lq[tid*4+1]=q1; lq[tid*4+2]=q2; lq[tid*4+3]=q3;
    lm[tid*4+0]=m0; lm[tid*4+1]=m1; lm[tid*4+2]=m2; lm[tid*4+3]=m3;
    __syncthreads();

    for (int off = 8; off; off >>= 1) {
        if (rg < off) {
            int o  = (tid + off * 16) * 4;
            int me = tid * 4;
            #pragma unroll
            for (int j = 0; j < 4; ++j) {
                ls[me+j] += ls[o+j];
                lq[me+j] += lq[o+j];
                lm[me+j]  = fmaxf(lm[me+j], lm[o+j]);
            }
        }
        __syncthreads();
    }

    if (rg == 0) {
        #pragma unroll
        for (int j = 0; j < 4; ++j) {
            int cell = b * 64 + d4 * 4 + j;
            atomicAdd(&g_sum[cell], ls[tid*4+j]);
            atomicAdd(&g_sq[cell],  lq[tid*4+j]);
            atomicMax(&g_max[cell], enc_f32(lm[tid*4+j]));
        }
    }
}

// ---- finalize stats + MLP + output ----------------------------------------
__global__ __launch_bounds__(256) void final_kernel(
    int N, long long E,
    const float* __restrict__ W1, const float* __restrict__ b1,
    const float* __restrict__ W2, const float* __restrict__ b2,
    const float* __restrict__ W3, const float* __restrict__ b3,
    float* __restrict__ out)
{
    __shared__ float gf[8][200];
    __shared__ float h1[8][64];
    __shared__ float h2[8][32];
    __shared__ float raw[8], rnd[8];

    const int tid = threadIdx.x;

    for (int i = tid; i < 512; i += 256) {
        int b = i >> 6, d = i & 63;
        float sum = g_sum[i], sq = g_sq[i];
        float mean = sum / (float)N;
        float var  = fmaxf(0.f, sq - sum * sum / (float)N) / (float)(N - 1);
        gf[b][d]       = mean;
        gf[b][64 + d]  = dec_f32(g_max[i]);
        gf[b][128 + d] = sqrtf(var);
    }
    if (tid < 32) {
        int b = tid >> 2, k = tid & 3;
        double dsum = (double)g_degSums[0];
        double dsq  = (double)g_degSums[1];
        double avg  = dsum / (double)N;
        double var  = (dsq - dsum * dsum / (double)N) / (double)(N - 1);
        long long num_edges = E / 2;
        double max_edges = (double)N * (double)(N - 1) / 2.0;
        float v;
        if      (k == 0) v = (float)avg;
        else if (k == 1) v = (float)sqrt(var);
        else if (k == 2) v = (float)((double)num_edges / max_edges);
        else             v = (float)(log((double)N + 1.0) / 10.0);
        gf[b][192 + k] = v;
    }
    __syncthreads();

    if (tid < 64) {
        int d = tid;
        for (int b = 0; b < 8; ++b) {
            float acc = b1[d];
            for (int k = 0; k < 196; ++k)
                acc = fmaf(gf[b][k], W1[k * 64 + d], acc);
            h1[b][d] = fmaxf(acc, 0.f);
        }
    }
    __syncthreads();

    if (tid < 32) {
        int d = tid;
        for (int b = 0; b < 8; ++b) {
            float acc = b2[d];
            for (int k = 0; k < 64; ++k)
                acc = fmaf(h1[b][k], W2[k * 32 + d], acc);
            h2[b][d] = fmaxf(acc, 0.f);
        }
    }
    __syncthreads();

    if (tid < 8) {
        float acc = b3[0];
        for (int k = 0; k < 32; ++k)
            acc = fmaf(h2[tid][k], W3[k], acc);
        float r = 1.f / (1.f + expf(-acc));
        raw[tid] = r;
        float cont = 3.0f + r * 47.0f;
        rnd[tid] = rintf(cont);
    }
    __syncthreads();

    if (tid == 0) {
        float sr = 0.f, sw = 0.f;
        for (int b = 0; b < 8; ++b) { sr += rnd[b]; sw += raw[b]; }
        out[0] = sr * 0.125f;
        out[1] = sw * 0.125f;
    }
}

// ---------------------------------------------------------------------------
extern "C" void kernel_launch(void* const* d_in, const int* in_sizes, int n_in,
                              void* d_out, int out_size, void* d_ws, size_t ws_size,
                              hipStream_t stream)
{
    const float* x  = (const float*)d_in[0];
    const int*   ei = (const int*)d_in[1];      // int32 per harness contract
    const float* W1 = (const float*)d_in[2];
    const float* b1 = (const float*)d_in[3];
    const float* W2 = (const float*)d_in[4];
    const float* b2 = (const float*)d_in[5];
    const float* W3 = (const float*)d_in[6];
    const float* b3 = (const float*)d_in[7];
    float* out = (float*)d_out;

    int N = in_sizes[0] / (8 * 64);            // B=8, D=64 fixed
    if (N > (NB << BSHIFT)) N = NB << BSHIFT;  // bucket-range guard
    int E = in_sizes[1] / 2;
    if (E > MAXE) E = MAXE;                    // scratch guard

    bucket_count_kernel  <<<SEG, 256, 0, stream>>>(ei, E, N);
    bucket_offset_kernel <<<1,   NB,  0, stream>>>();
    bucket_scatter_kernel<<<SEG, 256, 0, stream>>>(ei, E, N);
    bucket_hist_kernel   <<<NB,  256, 0, stream>>>();

    const int bpb = 256;
    const int rpb = (N + bpb - 1) / bpb;
    xstats_kernel<<<8 * bpb, 256, 0, stream>>>(x, N, bpb, rpb);

    final_kernel<<<1, 256, 0, stream>>>(N, (long long)E,
                                        W1, b1, W2, b2, W3, b3, out);
}